// Round 6
// baseline (573.115 us; speedup 1.0000x reference)
//
#include <hip/hip_runtime.h>
#include <hip/hip_bf16.h>

typedef unsigned short ushort_t;
typedef __bf16 bf16x8 __attribute__((ext_vector_type(8)));
typedef float f32x4 __attribute__((ext_vector_type(4)));

#define N_TOK 2048
#define DH    1024
#define FF    512
#define SFF   2816
#define NE    16

#define BM 128
#define BN 64
#define BK 64
#define LDK 72   // 64 + 8 pad (ushorts); 2-way bank alias on frag reads = free

__device__ __forceinline__ ushort_t f2bf(float f) {
  unsigned int x = __float_as_uint(f);
  unsigned int lsb = (x >> 16) & 1u;
  x += 0x7fffu + lsb;            // RNE; finite inputs
  return (ushort_t)(x >> 16);
}

// ---------------- straight fp32 -> bf16 convert, 4 tensors in one launch ----------------
__global__ void cvt4_kernel(const float* __restrict__ s0, ushort_t* __restrict__ d0, int n0_,
                            const float* __restrict__ s1, ushort_t* __restrict__ d1, int n1_,
                            const float* __restrict__ s2, ushort_t* __restrict__ d2, int n2_,
                            const float* __restrict__ s3, ushort_t* __restrict__ d3, int n3_) {
  const float* s; ushort_t* d; int n;
  switch (blockIdx.y) {
    case 0: s = s0; d = d0; n = n0_; break;
    case 1: s = s1; d = d1; n = n1_; break;
    case 2: s = s2; d = d2; n = n2_; break;
    default: s = s3; d = d3; n = n3_; break;
  }
  int i = (blockIdx.x * 256 + threadIdx.x) * 4;
  if (i >= n) return;
  float4 v = *(const float4*)(s + i);
  ushort4 o;
  o.x = f2bf(v.x); o.y = f2bf(v.y); o.z = f2bf(v.z); o.w = f2bf(v.w);
  *(ushort4*)(d + i) = o;
}

// ---------------- transpose + convert: in [K][N] fp32 -> out [N][K] bf16 (batched over e) ----
__global__ void trcvt_kernel(const float* __restrict__ in, ushort_t* __restrict__ out,
                             int K, int N) {
  __shared__ __align__(16) ushort_t lds[64][72];
  int e = blockIdx.z;
  int r0 = blockIdx.y * 64, c0 = blockIdx.x * 64;
  const float* src = in  + (size_t)e * K * N;
  ushort_t*    dst = out + (size_t)e * K * N;
  int t = threadIdx.x;
  int tr = t >> 2, tc = (t & 3) * 16;
  const float* p = src + (size_t)(r0 + tr) * N + c0 + tc;
  #pragma unroll
  for (int q = 0; q < 4; ++q) {
    float4 v = *(const float4*)(p + q * 4);
    lds[tr][tc + q * 4 + 0] = f2bf(v.x);
    lds[tr][tc + q * 4 + 1] = f2bf(v.y);
    lds[tr][tc + q * 4 + 2] = f2bf(v.z);
    lds[tr][tc + q * 4 + 3] = f2bf(v.w);
  }
  __syncthreads();
  ushort_t tmp[16];
  #pragma unroll
  for (int j = 0; j < 16; ++j) tmp[j] = lds[tc + j][tr];
  ushort_t* o = dst + (size_t)(c0 + tr) * K + r0 + tc;
  *(uint4*)o       = *(uint4*)&tmp[0];
  *(uint4*)(o + 8) = *(uint4*)&tmp[8];
}

// ---------------- router (fp32): logits, top-2, renorm, shared sigmoid gate ----------------
__global__ void router_kernel(const float* __restrict__ X, const float* __restrict__ GW,
                              const float* __restrict__ SGW,
                              int* __restrict__ sel, float* __restrict__ wtk,
                              float* __restrict__ sgate) {
  int wave = threadIdx.x >> 6, lane = threadIdx.x & 63;
  int n = blockIdx.x * 4 + wave;
  const float* x = X + (size_t)n * DH;
  int e = lane & 15, s = lane >> 4;
  const float* gw = GW + (size_t)e * DH;
  float lg = 0.f;
  for (int i = 0; i < 256; ++i) {
    int d = s * 256 + i;
    lg += x[d] * gw[d];
  }
  lg += __shfl_down(lg, 32);
  lg += __shfl_down(lg, 16);          // lanes 0..15 hold logits[e]

  float gd = 0.f;
  #pragma unroll
  for (int i = 0; i < 16; ++i) {
    int d = lane * 16 + i;
    gd += x[d] * SGW[d];
  }
  #pragma unroll
  for (int off = 32; off >= 1; off >>= 1) gd += __shfl_down(gd, off);

  float l[16];
  #pragma unroll
  for (int i = 0; i < 16; ++i) l[i] = __shfl(lg, i);

  if (lane == 0) {
    int i1 = 0; float v1 = l[0];
    #pragma unroll
    for (int i = 1; i < 16; ++i) if (l[i] > v1) { v1 = l[i]; i1 = i; }
    int i2 = -1; float v2 = -1e30f;
    #pragma unroll
    for (int i = 0; i < 16; ++i) { if (i == i1) continue; if (l[i] > v2) { v2 = l[i]; i2 = i; } }
    float p2 = __expf(v2 - v1);          // softmax denom cancels in renorm
    float inv = 1.f / (1.f + p2);
    sel[n * 2 + 0] = i1; sel[n * 2 + 1] = i2;
    wtk[n * 2 + 0] = inv; wtk[n * 2 + 1] = p2 * inv;
    sgate[n] = 1.f / (1.f + __expf(-gd));
  }
}

// ---------------- single-block scatter: compact per-expert token lists + slot map ----------
__global__ void scatter_kernel(const int* __restrict__ sel,
                               int* __restrict__ toks, int* __restrict__ slot_of,
                               int* __restrict__ offs) {
  __shared__ int cnt[NE], bas[NE];
  int t = threadIdx.x;
  if (t < NE) cnt[t] = 0;
  __syncthreads();
  for (int i = t; i < N_TOK * 2; i += 256) atomicAdd(&cnt[sel[i]], 1);
  __syncthreads();
  if (t == 0) {
    int s = 0;
    for (int e = 0; e < NE; ++e) { bas[e] = s; offs[e] = s; s += cnt[e]; }
    offs[NE] = s;
  }
  __syncthreads();
  if (t < NE) cnt[t] = 0;
  __syncthreads();
  for (int i = t; i < N_TOK * 2; i += 256) {
    int e = sel[i];
    int p = atomicAdd(&cnt[e], 1);
    int slot = bas[e] + p;
    toks[slot] = i >> 1;
    slot_of[i] = slot;
  }
}

// ---------------- merged gate_up + SwiGLU (shared blocks [0,704), expert [704,2752)) ------
// All operands bf16 NT. K = 1024 both paths.
__global__ __launch_bounds__(256, 3) void gateup_kernel(
    const ushort_t* __restrict__ XB, const ushort_t* __restrict__ WGUT,
    const ushort_t* __restrict__ SWGB, const ushort_t* __restrict__ SWUB,
    ushort_t* __restrict__ HX, ushort_t* __restrict__ HS,
    const int* __restrict__ toks, const int* __restrict__ offs) {
  __shared__ __align__(16) ushort_t As[BM][LDK];
  __shared__ __align__(16) ushort_t Bgs[BN][LDK];
  __shared__ __align__(16) ushort_t Bus[BN][LDK];
  const int K = DH, NT = K / BK;

  int bid = blockIdx.x;
  int t = threadIdx.x;
  int wave = t >> 6, lane = t & 63;
  int wm = wave & 1, wn = wave >> 1;
  int qd = lane >> 4, l16 = lane & 15;
  int sr = t >> 3, sc = (t & 7) * 8;

  const ushort_t *arow[4], *bgrow[2], *burow[2];
  int m0, n0, M, base, is_exp;

  if (bid < 704) {
    is_exp = 0; base = 0; M = N_TOK;
    n0 = (bid % 44) * BN; m0 = (bid / 44) * BM;
    #pragma unroll
    for (int p = 0; p < 4; ++p)
      arow[p] = XB + (size_t)(m0 + sr + 32 * p) * K + sc;
    #pragma unroll
    for (int p = 0; p < 2; ++p) {
      bgrow[p] = SWGB + (size_t)(n0 + sr + 32 * p) * K + sc;
      burow[p] = SWUB + (size_t)(n0 + sr + 32 * p) * K + sc;
    }
  } else {
    is_exp = 1;
    int b2 = bid - 704;
    int e = b2 >> 7, rem = b2 & 127;
    n0 = (rem & 7) * BN; m0 = (rem >> 3) * BM;
    base = offs[e]; M = offs[e + 1] - base;
    if (m0 >= M) return;
    const ushort_t* W = WGUT + (size_t)e * DH * (2 * FF);   // [1024 n][1024 k]
    #pragma unroll
    for (int p = 0; p < 4; ++p) {
      int m = m0 + sr + 32 * p;
      int mm = m < M ? m : (M - 1);
      arow[p] = XB + (size_t)toks[base + mm] * K + sc;
    }
    #pragma unroll
    for (int p = 0; p < 2; ++p) {
      bgrow[p] = W + (size_t)(n0 + sr + 32 * p) * K + sc;          // gate rows 0..511
      burow[p] = W + (size_t)(FF + n0 + sr + 32 * p) * K + sc;     // up rows 512..1023
    }
  }

  uint4 ar[4], bgr[2], bur[2];
  #pragma unroll
  for (int p = 0; p < 4; ++p) ar[p] = *(const uint4*)(arow[p]);
  #pragma unroll
  for (int p = 0; p < 2; ++p) {
    bgr[p] = *(const uint4*)(bgrow[p]);
    bur[p] = *(const uint4*)(burow[p]);
  }

  f32x4 accg[4][2], accu[4][2];
  #pragma unroll
  for (int i = 0; i < 4; ++i)
    #pragma unroll
    for (int j = 0; j < 2; ++j) {
      accg[i][j] = (f32x4){0.f, 0.f, 0.f, 0.f};
      accu[i][j] = (f32x4){0.f, 0.f, 0.f, 0.f};
    }

  for (int kt = 0; kt < NT; ++kt) {
    #pragma unroll
    for (int p = 0; p < 4; ++p)
      *(uint4*)&As[sr + 32 * p][sc] = ar[p];
    #pragma unroll
    for (int p = 0; p < 2; ++p) {
      *(uint4*)&Bgs[sr + 32 * p][sc] = bgr[p];
      *(uint4*)&Bus[sr + 32 * p][sc] = bur[p];
    }
    __syncthreads();
    if (kt + 1 < NT) {
      int ko = (kt + 1) * BK;
      #pragma unroll
      for (int p = 0; p < 4; ++p) ar[p] = *(const uint4*)(arow[p] + ko);
      #pragma unroll
      for (int p = 0; p < 2; ++p) {
        bgr[p] = *(const uint4*)(bgrow[p] + ko);
        bur[p] = *(const uint4*)(burow[p] + ko);
      }
    }
    #pragma unroll
    for (int ks = 0; ks < 2; ++ks) {
      int kk = ks * 32 + qd * 8;
      bf16x8 af[4], bgf[2], buf[2];
      #pragma unroll
      for (int i = 0; i < 4; ++i)
        af[i] = *(const bf16x8*)&As[wm * 64 + i * 16 + l16][kk];
      #pragma unroll
      for (int j = 0; j < 2; ++j) {
        bgf[j] = *(const bf16x8*)&Bgs[wn * 32 + j * 16 + l16][kk];
        buf[j] = *(const bf16x8*)&Bus[wn * 32 + j * 16 + l16][kk];
      }
      #pragma unroll
      for (int i = 0; i < 4; ++i)
        #pragma unroll
        for (int j = 0; j < 2; ++j) {
          accg[i][j] = __builtin_amdgcn_mfma_f32_16x16x32_bf16(af[i], bgf[j], accg[i][j], 0, 0, 0);
          accu[i][j] = __builtin_amdgcn_mfma_f32_16x16x32_bf16(af[i], buf[j], accu[i][j], 0, 0, 0);
        }
    }
    __syncthreads();
  }

  #pragma unroll
  for (int i = 0; i < 4; ++i)
    #pragma unroll
    for (int r = 0; r < 4; ++r) {
      int m = m0 + wm * 64 + i * 16 + qd * 4 + r;
      if (m >= M) continue;
      #pragma unroll
      for (int j = 0; j < 2; ++j) {
        float g = accg[i][j][r], u = accu[i][j][r];
        float h = g / (1.f + __expf(-g)) * u;   // silu(g)*u
        int col = n0 + wn * 32 + j * 16 + l16;
        if (is_exp) HX[(size_t)(base + m) * FF + col] = f2bf(h);
        else        HS[(size_t)m * SFF + col] = f2bf(h);
      }
    }
}

// ---------------- merged down (shared blocks [0,256), expert [256,4352)) ----------------
// shared: sd[tok][n] = hs @ swd^T (fp32, no gate). expert: exp_out[slot][n] = hx @ Wd (fp32, no weight).
__global__ __launch_bounds__(256, 4) void down_kernel(
    const ushort_t* __restrict__ HX, const ushort_t* __restrict__ HS,
    const ushort_t* __restrict__ WDNT, const ushort_t* __restrict__ SWDB,
    float* __restrict__ sd, float* __restrict__ exp_out,
    const int* __restrict__ offs) {
  __shared__ __align__(16) ushort_t As[BM][LDK];
  __shared__ __align__(16) ushort_t Bs[BN][LDK];

  int bid = blockIdx.x;
  int t = threadIdx.x;
  int wave = t >> 6, lane = t & 63;
  int wm = wave & 1, wn = wave >> 1;
  int qd = lane >> 4, l16 = lane & 15;
  int sr = t >> 3, sc = (t & 7) * 8;

  const ushort_t *arow[4], *brow[2];
  float* outp;
  int m0, n0, M, NT, K;

  if (bid < 256) {
    // shared: M=2048, N=1024, K=2816
    M = N_TOK; K = SFF; NT = K / BK;
    m0 = (bid >> 4) * BM; n0 = (bid & 15) * BN;
    #pragma unroll
    for (int p = 0; p < 4; ++p)
      arow[p] = HS + (size_t)(m0 + sr + 32 * p) * SFF + sc;
    #pragma unroll
    for (int p = 0; p < 2; ++p)
      brow[p] = SWDB + (size_t)(n0 + sr + 32 * p) * SFF + sc;
    outp = sd;
  } else {
    int b2 = bid - 256;
    int e = b2 >> 8, rem = b2 & 255;
    n0 = (rem & 15) * BN; m0 = (rem >> 4) * BM;
    int base = offs[e];
    M = offs[e + 1] - base;
    if (m0 >= M) return;
    K = FF; NT = K / BK;
    const ushort_t* A = HX + (size_t)base * FF;
    const ushort_t* W = WDNT + (size_t)e * DH * FF;   // [1024 n][512 k]
    #pragma unroll
    for (int p = 0; p < 4; ++p) {
      int m = m0 + sr + 32 * p;
      int mm = m < M ? m : (M - 1);
      arow[p] = A + (size_t)mm * FF + sc;
    }
    #pragma unroll
    for (int p = 0; p < 2; ++p)
      brow[p] = W + (size_t)(n0 + sr + 32 * p) * FF + sc;
    outp = exp_out + (size_t)base * DH;
  }

  uint4 ar[4], br[2];
  #pragma unroll
  for (int p = 0; p < 4; ++p) ar[p] = *(const uint4*)(arow[p]);
  #pragma unroll
  for (int p = 0; p < 2; ++p) br[p] = *(const uint4*)(brow[p]);

  f32x4 c[4][2];
  #pragma unroll
  for (int i = 0; i < 4; ++i)
    #pragma unroll
    for (int j = 0; j < 2; ++j) c[i][j] = (f32x4){0.f, 0.f, 0.f, 0.f};

  for (int kt = 0; kt < NT; ++kt) {
    #pragma unroll
    for (int p = 0; p < 4; ++p)
      *(uint4*)&As[sr + 32 * p][sc] = ar[p];
    #pragma unroll
    for (int p = 0; p < 2; ++p)
      *(uint4*)&Bs[sr + 32 * p][sc] = br[p];
    __syncthreads();
    if (kt + 1 < NT) {
      int ko = (kt + 1) * BK;
      #pragma unroll
      for (int p = 0; p < 4; ++p) ar[p] = *(const uint4*)(arow[p] + ko);
      #pragma unroll
      for (int p = 0; p < 2; ++p) br[p] = *(const uint4*)(brow[p] + ko);
    }
    #pragma unroll
    for (int ks = 0; ks < 2; ++ks) {
      int kk = ks * 32 + qd * 8;
      bf16x8 af[4], bf[2];
      #pragma unroll
      for (int i = 0; i < 4; ++i)
        af[i] = *(const bf16x8*)&As[wm * 64 + i * 16 + l16][kk];
      #pragma unroll
      for (int j = 0; j < 2; ++j)
        bf[j] = *(const bf16x8*)&Bs[wn * 32 + j * 16 + l16][kk];
      #pragma unroll
      for (int i = 0; i < 4; ++i)
        #pragma unroll
        for (int j = 0; j < 2; ++j)
          c[i][j] = __builtin_amdgcn_mfma_f32_16x16x32_bf16(af[i], bf[j], c[i][j], 0, 0, 0);
    }
    __syncthreads();
  }

  #pragma unroll
  for (int i = 0; i < 4; ++i)
    #pragma unroll
    for (int r = 0; r < 4; ++r) {
      int m = m0 + wm * 64 + i * 16 + qd * 4 + r;
      if (m >= M) continue;
      #pragma unroll
      for (int j = 0; j < 2; ++j) {
        int n = n0 + wn * 32 + j * 16 + l16;
        outp[(size_t)m * DH + n] = c[i][j][r];
      }
    }
}

// ---------------- combine: out[tok] = sg*sd + w0*exp_out[s0] + w1*exp_out[s1] ----------------
__global__ void combine_kernel(const float4* __restrict__ sd4, const float4* __restrict__ e4,
                               const float* __restrict__ sgate, const float* __restrict__ wtk,
                               const int* __restrict__ slot_of, float4* __restrict__ out4) {
  int n = blockIdx.x, t = threadIdx.x;
  float sg = sgate[n];
  float w0 = wtk[n * 2 + 0], w1 = wtk[n * 2 + 1];
  int s0 = slot_of[n * 2 + 0], s1 = slot_of[n * 2 + 1];
  float4 s = sd4[(size_t)n * 256 + t];
  float4 a = e4[(size_t)s0 * 256 + t];
  float4 b = e4[(size_t)s1 * 256 + t];
  float4 o;
  o.x = sg * s.x + w0 * a.x + w1 * b.x;
  o.y = sg * s.y + w0 * a.y + w1 * b.y;
  o.z = sg * s.z + w0 * a.z + w1 * b.z;
  o.w = sg * s.w + w0 * a.w + w1 * b.w;
  out4[(size_t)n * 256 + t] = o;
}

// ---------------- launcher ----------------
extern "C" void kernel_launch(void* const* d_in, const int* in_sizes, int n_in,
                              void* d_out, int out_size, void* d_ws, size_t ws_size,
                              hipStream_t stream) {
  const float* x    = (const float*)d_in[0];   // [2048,1024]
  const float* gw   = (const float*)d_in[1];   // [16,1024]
  const float* wgu  = (const float*)d_in[2];   // [16,1024,1024]  (k-major)
  const float* wdn  = (const float*)d_in[3];   // [16,512,1024]   (k-major)
  const float* swg  = (const float*)d_in[4];   // [2816,1024]  NT
  const float* swu  = (const float*)d_in[5];   // [2816,1024]  NT
  const float* swd  = (const float*)d_in[6];   // [1024,2816]  NT
  const float* sgw  = (const float*)d_in[7];   // [1,1024]
  float* out = (float*)d_out;

  char* ws = (char*)d_ws;
  constexpr size_t OFF_XB   = 0;                                  //  4,194,304
  constexpr size_t OFF_WGUT = OFF_XB   + (size_t)N_TOK * DH * 2;
  constexpr size_t OFF_WDNT = OFF_WGUT + (size_t)NE * DH * 2 * FF * 2;   // +33,554,432
  constexpr size_t OFF_SWGB = OFF_WDNT + (size_t)NE * DH * FF * 2;       // +16,777,216
  constexpr size_t OFF_SWUB = OFF_SWGB + (size_t)SFF * DH * 2;           // +5,767,168
  constexpr size_t OFF_SWDB = OFF_SWUB + (size_t)SFF * DH * 2;
  constexpr size_t OFF_HS   = OFF_SWDB + (size_t)SFF * DH * 2;
  constexpr size_t OFF_HX   = OFF_HS   + (size_t)N_TOK * SFF * 2;        // +11,534,336
  constexpr size_t OFF_EXPO = OFF_HX   + (size_t)4096 * FF * 2;          // +4,194,304
  constexpr size_t OFF_SD   = OFF_EXPO + (size_t)4096 * DH * 4;          // +16,777,216
  constexpr size_t OFF_TOK  = OFF_SD   + (size_t)N_TOK * DH * 4;         // +8,388,608
  constexpr size_t OFF_OFFS = OFF_TOK  + 4096 * 4;
  constexpr size_t OFF_SEL  = OFF_OFFS + 32 * 4;
  constexpr size_t OFF_WTK  = OFF_SEL  + 4096 * 4;
  constexpr size_t OFF_SG   = OFF_WTK  + 4096 * 4;
  constexpr size_t OFF_SLOT = OFF_SG   + 2048 * 4;                // end ~112.8 MB

  ushort_t* xb    = (ushort_t*)(ws + OFF_XB);
  ushort_t* wgut  = (ushort_t*)(ws + OFF_WGUT);
  ushort_t* wdnt  = (ushort_t*)(ws + OFF_WDNT);
  ushort_t* swgb  = (ushort_t*)(ws + OFF_SWGB);
  ushort_t* swub  = (ushort_t*)(ws + OFF_SWUB);
  ushort_t* swdb  = (ushort_t*)(ws + OFF_SWDB);
  ushort_t* hs    = (ushort_t*)(ws + OFF_HS);
  ushort_t* hx    = (ushort_t*)(ws + OFF_HX);
  float*    expo  = (float*)(ws + OFF_EXPO);
  float*    sd    = (float*)(ws + OFF_SD);
  int*      toks  = (int*)(ws + OFF_TOK);
  int*      offs  = (int*)(ws + OFF_OFFS);
  int*      sel   = (int*)(ws + OFF_SEL);
  float*    wtk   = (float*)(ws + OFF_WTK);
  float*    sgate = (float*)(ws + OFF_SG);
  int*      slot_of = (int*)(ws + OFF_SLOT);

  // pre-convert: x (2.1M), swg/swu/swd (2.88M each); grid covers max, guarded
  cvt4_kernel<<<dim3(2816, 4), 256, 0, stream>>>(
      x, xb, N_TOK * DH, swg, swgb, SFF * DH, swu, swub, SFF * DH, swd, swdb, DH * SFF);
  // transpose+convert expert weights to NT
  trcvt_kernel<<<dim3(16, 16, NE), 256, 0, stream>>>(wgu, wgut, DH, 2 * FF);  // [1024k][1024n]->[1024n][1024k]
  trcvt_kernel<<<dim3(16, 8, NE), 256, 0, stream>>>(wdn, wdnt, FF, DH);       // [512k][1024n]->[1024n][512k]
  router_kernel<<<N_TOK / 4, 256, 0, stream>>>(x, gw, sgw, sel, wtk, sgate);
  scatter_kernel<<<1, 256, 0, stream>>>(sel, toks, slot_of, offs);
  // gateup: shared 16m*44n = 704, expert 16e*16m*8n = 2048
  gateup_kernel<<<704 + 2048, 256, 0, stream>>>(xb, wgut, swgb, swub, hx, hs, toks, offs);
  // down: shared 16m*16n = 256, expert 16e*16m*16n = 4096
  down_kernel<<<256 + 4096, 256, 0, stream>>>(hx, hs, wdnt, swdb, sd, expo, offs);
  combine_kernel<<<N_TOK, 256, 0, stream>>>(
      (const float4*)sd, (const float4*)expo, sgate, wtk, slot_of, (float4*)out);
}

// Round 7
// 409.308 us; speedup vs baseline: 1.4002x; 1.4002x over previous
//
#include <hip/hip_runtime.h>
#include <hip/hip_bf16.h>

typedef unsigned short ushort_t;
typedef __bf16 bf16x8 __attribute__((ext_vector_type(8)));
typedef float f32x4 __attribute__((ext_vector_type(4)));

#define N_TOK 2048
#define DH    1024
#define FF    512
#define SFF   2816
#define NE    16

#define BM 128
#define BN 64
#define BK 64
#define LDK 72   // 64 + 8 pad (ushorts)

__device__ __forceinline__ ushort_t f2bf(float f) {
  unsigned int x = __float_as_uint(f);
  unsigned int lsb = (x >> 16) & 1u;
  x += 0x7fffu + lsb;            // RNE; finite inputs
  return (ushort_t)(x >> 16);
}
__device__ __forceinline__ float bf2f(ushort_t u) {
  union { unsigned int i; float f; } v; v.i = ((unsigned int)u) << 16; return v.f;
}
__device__ __forceinline__ uint4 cvt8v(const float4 a, const float4 b) {
  union { ushort_t u[8]; uint4 v; } r;
  r.u[0] = f2bf(a.x); r.u[1] = f2bf(a.y); r.u[2] = f2bf(a.z); r.u[3] = f2bf(a.w);
  r.u[4] = f2bf(b.x); r.u[5] = f2bf(b.y); r.u[6] = f2bf(b.z); r.u[7] = f2bf(b.w);
  return r.v;
}
__device__ __forceinline__ uint4 ld_cvt8(const float* __restrict__ p) {
  float4 a = *(const float4*)p;
  float4 b = *(const float4*)(p + 4);
  return cvt8v(a, b);
}

// ---------------- router (fp32): logits, top-2, renorm, shared sigmoid gate ----------------
__global__ void router_kernel(const float* __restrict__ X, const float* __restrict__ GW,
                              const float* __restrict__ SGW,
                              int* __restrict__ sel, float* __restrict__ wtk,
                              float* __restrict__ sgate) {
  int wave = threadIdx.x >> 6, lane = threadIdx.x & 63;
  int n = blockIdx.x * 4 + wave;
  const float* x = X + (size_t)n * DH;
  int e = lane & 15, s = lane >> 4;
  const float* gw = GW + (size_t)e * DH;
  float lg = 0.f;
  for (int i = 0; i < 256; ++i) {
    int d = s * 256 + i;
    lg += x[d] * gw[d];
  }
  lg += __shfl_down(lg, 32);
  lg += __shfl_down(lg, 16);          // lanes 0..15 hold logits[e]

  float gd = 0.f;
  #pragma unroll
  for (int i = 0; i < 16; ++i) {
    int d = lane * 16 + i;
    gd += x[d] * SGW[d];
  }
  #pragma unroll
  for (int off = 32; off >= 1; off >>= 1) gd += __shfl_down(gd, off);

  float l[16];
  #pragma unroll
  for (int i = 0; i < 16; ++i) l[i] = __shfl(lg, i);

  if (lane == 0) {
    int i1 = 0; float v1 = l[0];
    #pragma unroll
    for (int i = 1; i < 16; ++i) if (l[i] > v1) { v1 = l[i]; i1 = i; }
    int i2 = -1; float v2 = -1e30f;
    #pragma unroll
    for (int i = 0; i < 16; ++i) { if (i == i1) continue; if (l[i] > v2) { v2 = l[i]; i2 = i; } }
    float p2 = __expf(v2 - v1);          // softmax denom cancels in renorm
    float inv = 1.f / (1.f + p2);
    sel[n * 2 + 0] = i1; sel[n * 2 + 1] = i2;
    wtk[n * 2 + 0] = inv; wtk[n * 2 + 1] = p2 * inv;
    sgate[n] = 1.f / (1.f + __expf(-gd));
  }
}

// ---------------- single-block scatter ----------------
__global__ void scatter_kernel(const int* __restrict__ sel,
                               int* __restrict__ toks, int* __restrict__ slot_of,
                               int* __restrict__ offs) {
  __shared__ int cnt[NE], bas[NE];
  int t = threadIdx.x;
  if (t < NE) cnt[t] = 0;
  __syncthreads();
  for (int i = t; i < N_TOK * 2; i += 256) atomicAdd(&cnt[sel[i]], 1);
  __syncthreads();
  if (t == 0) {
    int s = 0;
    for (int e = 0; e < NE; ++e) { bas[e] = s; offs[e] = s; s += cnt[e]; }
    offs[NE] = s;
  }
  __syncthreads();
  if (t < NE) cnt[t] = 0;
  __syncthreads();
  for (int i = t; i < N_TOK * 2; i += 256) {
    int e = sel[i];
    int p = atomicAdd(&cnt[e], 1);
    int slot = bas[e] + p;
    toks[slot] = i >> 1;
    slot_of[i] = slot;
  }
}

// ---------------- merged gate_up + SwiGLU (shared [0,704), expert [704,2752)) ----------------
// fp32 sources, in-register cvt. Coalesced uint4 stores via LDS bounce.
__global__ __launch_bounds__(256, 3) void gateup_kernel(
    const float* __restrict__ X, const float* __restrict__ WGU,
    const float* __restrict__ SWG, const float* __restrict__ SWU,
    ushort_t* __restrict__ HX, ushort_t* __restrict__ HS,
    const int* __restrict__ toks, const int* __restrict__ offs) {
  __shared__ __align__(16) ushort_t As[BM][LDK];
  __shared__ __align__(16) ushort_t Bgs[BN][LDK];
  __shared__ __align__(16) ushort_t Bus[BN][LDK];
  const int K = DH, NT = K / BK;

  int bid = blockIdx.x;
  int t = threadIdx.x;
  int wave = t >> 6, lane = t & 63;
  int wm = wave & 1, wn = wave >> 1;
  int qd = lane >> 4, l16 = lane & 15;
  int sr = t >> 3, sc = (t & 7) * 8;

  f32x4 accg[4][2], accu[4][2];
  #pragma unroll
  for (int i = 0; i < 4; ++i)
    #pragma unroll
    for (int j = 0; j < 2; ++j) {
      accg[i][j] = (f32x4){0.f, 0.f, 0.f, 0.f};
      accu[i][j] = (f32x4){0.f, 0.f, 0.f, 0.f};
    }

  int m0, n0, M, base, is_exp;

  if (bid < 704) {
    // ---------- shared path: NT fp32 B rows ----------
    is_exp = 0; base = 0; M = N_TOK;
    n0 = (bid % 44) * BN; m0 = (bid / 44) * BM;
    const float* arow[4];
    const float *bgrow[2], *burow[2];
    #pragma unroll
    for (int p = 0; p < 4; ++p)
      arow[p] = X + (size_t)(m0 + sr + 32 * p) * K + sc;
    #pragma unroll
    for (int p = 0; p < 2; ++p) {
      bgrow[p] = SWG + (size_t)(n0 + sr + 32 * p) * K + sc;
      burow[p] = SWU + (size_t)(n0 + sr + 32 * p) * K + sc;
    }
    uint4 ar[4], bgr[2], bur[2];
    #pragma unroll
    for (int p = 0; p < 4; ++p) ar[p] = ld_cvt8(arow[p]);
    #pragma unroll
    for (int p = 0; p < 2; ++p) { bgr[p] = ld_cvt8(bgrow[p]); bur[p] = ld_cvt8(burow[p]); }

    for (int kt = 0; kt < NT; ++kt) {
      #pragma unroll
      for (int p = 0; p < 4; ++p)
        *(uint4*)&As[sr + 32 * p][sc] = ar[p];
      #pragma unroll
      for (int p = 0; p < 2; ++p) {
        *(uint4*)&Bgs[sr + 32 * p][sc] = bgr[p];
        *(uint4*)&Bus[sr + 32 * p][sc] = bur[p];
      }
      __syncthreads();
      if (kt + 1 < NT) {
        int ko = (kt + 1) * BK;
        #pragma unroll
        for (int p = 0; p < 4; ++p) ar[p] = ld_cvt8(arow[p] + ko);
        #pragma unroll
        for (int p = 0; p < 2; ++p) { bgr[p] = ld_cvt8(bgrow[p] + ko); bur[p] = ld_cvt8(burow[p] + ko); }
      }
      #pragma unroll
      for (int ks = 0; ks < 2; ++ks) {
        int kk = ks * 32 + qd * 8;
        bf16x8 af[4], bgf[2], buf[2];
        #pragma unroll
        for (int i = 0; i < 4; ++i)
          af[i] = *(const bf16x8*)&As[wm * 64 + i * 16 + l16][kk];
        #pragma unroll
        for (int j = 0; j < 2; ++j) {
          bgf[j] = *(const bf16x8*)&Bgs[wn * 32 + j * 16 + l16][kk];
          buf[j] = *(const bf16x8*)&Bus[wn * 32 + j * 16 + l16][kk];
        }
        #pragma unroll
        for (int i = 0; i < 4; ++i)
          #pragma unroll
          for (int j = 0; j < 2; ++j) {
            accg[i][j] = __builtin_amdgcn_mfma_f32_16x16x32_bf16(af[i], bgf[j], accg[i][j], 0, 0, 0);
            accu[i][j] = __builtin_amdgcn_mfma_f32_16x16x32_bf16(af[i], buf[j], accu[i][j], 0, 0, 0);
          }
      }
      __syncthreads();
    }
  } else {
    // ---------- expert path: B = wgu[e] [1024 k][1024 n], gather-transpose staged ----------
    is_exp = 1;
    int b2 = bid - 704;
    int e = b2 >> 7, rem = b2 & 127;
    n0 = (rem & 7) * BN; m0 = (rem >> 3) * BM;
    base = offs[e]; M = offs[e + 1] - base;
    if (m0 >= M) return;
    const float* W = WGU + (size_t)e * DH * (2 * FF);
    int tn = t & 63, tk = (t >> 6) * 16;

    const float* arow[4];
    #pragma unroll
    for (int p = 0; p < 4; ++p) {
      int m = m0 + sr + 32 * p;
      int mm = m < M ? m : (M - 1);
      arow[p] = X + (size_t)toks[base + mm] * K + sc;
    }
    const float* wkb = W + (size_t)tk * (2 * FF) + n0 + tn;

    uint4 ar[4];
    float bgr[16], bur[16];
    #pragma unroll
    for (int p = 0; p < 4; ++p) ar[p] = ld_cvt8(arow[p]);
    #pragma unroll
    for (int j = 0; j < 16; ++j) {
      bgr[j] = wkb[(size_t)j * (2 * FF)];
      bur[j] = wkb[(size_t)j * (2 * FF) + FF];
    }

    for (int kt = 0; kt < NT; ++kt) {
      #pragma unroll
      for (int p = 0; p < 4; ++p)
        *(uint4*)&As[sr + 32 * p][sc] = ar[p];
      {
        union { ushort_t u[8]; uint4 v; } g0, g1, u0, u1;
        #pragma unroll
        for (int j = 0; j < 8; ++j) {
          g0.u[j] = f2bf(bgr[j]); g1.u[j] = f2bf(bgr[8 + j]);
          u0.u[j] = f2bf(bur[j]); u1.u[j] = f2bf(bur[8 + j]);
        }
        *(uint4*)&Bgs[tn][tk]     = g0.v;
        *(uint4*)&Bgs[tn][tk + 8] = g1.v;
        *(uint4*)&Bus[tn][tk]     = u0.v;
        *(uint4*)&Bus[tn][tk + 8] = u1.v;
      }
      __syncthreads();
      if (kt + 1 < NT) {
        int ko = (kt + 1) * BK;
        #pragma unroll
        for (int p = 0; p < 4; ++p) ar[p] = ld_cvt8(arow[p] + ko);
        const float* wk = wkb + (size_t)ko * (2 * FF);
        #pragma unroll
        for (int j = 0; j < 16; ++j) {
          bgr[j] = wk[(size_t)j * (2 * FF)];
          bur[j] = wk[(size_t)j * (2 * FF) + FF];
        }
      }
      #pragma unroll
      for (int ks = 0; ks < 2; ++ks) {
        int kk = ks * 32 + qd * 8;
        bf16x8 af[4], bgf[2], buf[2];
        #pragma unroll
        for (int i = 0; i < 4; ++i)
          af[i] = *(const bf16x8*)&As[wm * 64 + i * 16 + l16][kk];
        #pragma unroll
        for (int j = 0; j < 2; ++j) {
          bgf[j] = *(const bf16x8*)&Bgs[wn * 32 + j * 16 + l16][kk];
          buf[j] = *(const bf16x8*)&Bus[wn * 32 + j * 16 + l16][kk];
        }
        #pragma unroll
        for (int i = 0; i < 4; ++i)
          #pragma unroll
          for (int j = 0; j < 2; ++j) {
            accg[i][j] = __builtin_amdgcn_mfma_f32_16x16x32_bf16(af[i], bgf[j], accg[i][j], 0, 0, 0);
            accu[i][j] = __builtin_amdgcn_mfma_f32_16x16x32_bf16(af[i], buf[j], accu[i][j], 0, 0, 0);
          }
      }
      __syncthreads();
    }
  }

  // ---------- epilogue: SwiGLU -> LDS bounce -> coalesced uint4 stores ----------
  #pragma unroll
  for (int i = 0; i < 4; ++i)
    #pragma unroll
    for (int r = 0; r < 4; ++r) {
      int row = wm * 64 + i * 16 + qd * 4 + r;
      #pragma unroll
      for (int j = 0; j < 2; ++j) {
        float g = accg[i][j][r], u = accu[i][j][r];
        float h = g / (1.f + __expf(-g)) * u;   // silu(g)*u
        As[row][wn * 32 + j * 16 + l16] = f2bf(h);
      }
    }
  __syncthreads();
  if (is_exp) {
    #pragma unroll
    for (int p = 0; p < 4; ++p) {
      int m = m0 + sr + 32 * p;
      if (m < M)
        *(uint4*)(HX + (size_t)(base + m) * FF + n0 + sc) = *(uint4*)&As[sr + 32 * p][sc];
    }
  } else {
    #pragma unroll
    for (int p = 0; p < 4; ++p) {
      int m = m0 + sr + 32 * p;
      *(uint4*)(HS + (size_t)m * SFF + n0 + sc) = *(uint4*)&As[sr + 32 * p][sc];
    }
  }
}

// ---------------- merged down (shared split-K=2 [0,512), expert [512,4608)) ----------------
// shared: sdk[kz][tok][n] = partial hs @ swd^T (bf16). expert: expo[slot][n] = hx @ Wd (bf16).
__global__ __launch_bounds__(256, 4) void down_kernel(
    const ushort_t* __restrict__ HX, const ushort_t* __restrict__ HS,
    const float* __restrict__ WDN, const float* __restrict__ SWD,
    ushort_t* __restrict__ SD0, ushort_t* __restrict__ SD1,
    ushort_t* __restrict__ EXPO, const int* __restrict__ offs) {
  __shared__ __align__(16) ushort_t As[BM][LDK];
  __shared__ __align__(16) ushort_t Bs[BN][LDK];

  int bid = blockIdx.x;
  int t = threadIdx.x;
  int wave = t >> 6, lane = t & 63;
  int wm = wave & 1, wn = wave >> 1;
  int qd = lane >> 4, l16 = lane & 15;
  int sr = t >> 3, sc = (t & 7) * 8;

  f32x4 c[4][2];
  #pragma unroll
  for (int i = 0; i < 4; ++i)
    #pragma unroll
    for (int j = 0; j < 2; ++j) c[i][j] = (f32x4){0.f, 0.f, 0.f, 0.f};

  int m0, n0, M, base_row;
  ushort_t* outp;

  if (bid < 512) {
    // ---------- shared path: A bf16 NT, B fp32 NT, K chunk 1408 ----------
    int kz = bid >> 8, rem = bid & 255;
    m0 = (rem >> 4) * BM; n0 = (rem & 15) * BN;
    M = N_TOK; base_row = 0;
    const int KC = SFF / 2, NT = KC / BK;   // 22
    int kb = kz * KC;
    outp = kz ? SD1 : SD0;

    const ushort_t* arow[4];
    const float* brow[2];
    #pragma unroll
    for (int p = 0; p < 4; ++p)
      arow[p] = HS + (size_t)(m0 + sr + 32 * p) * SFF + kb + sc;
    #pragma unroll
    for (int p = 0; p < 2; ++p)
      brow[p] = SWD + (size_t)(n0 + sr + 32 * p) * SFF + kb + sc;

    uint4 ar[4], br[2];
    #pragma unroll
    for (int p = 0; p < 4; ++p) ar[p] = *(const uint4*)(arow[p]);
    #pragma unroll
    for (int p = 0; p < 2; ++p) br[p] = ld_cvt8(brow[p]);

    for (int kt = 0; kt < NT; ++kt) {
      #pragma unroll
      for (int p = 0; p < 4; ++p)
        *(uint4*)&As[sr + 32 * p][sc] = ar[p];
      #pragma unroll
      for (int p = 0; p < 2; ++p)
        *(uint4*)&Bs[sr + 32 * p][sc] = br[p];
      __syncthreads();
      if (kt + 1 < NT) {
        int ko = (kt + 1) * BK;
        #pragma unroll
        for (int p = 0; p < 4; ++p) ar[p] = *(const uint4*)(arow[p] + ko);
        #pragma unroll
        for (int p = 0; p < 2; ++p) br[p] = ld_cvt8(brow[p] + ko);
      }
      #pragma unroll
      for (int ks = 0; ks < 2; ++ks) {
        int kk = ks * 32 + qd * 8;
        bf16x8 af[4], bf[2];
        #pragma unroll
        for (int i = 0; i < 4; ++i)
          af[i] = *(const bf16x8*)&As[wm * 64 + i * 16 + l16][kk];
        #pragma unroll
        for (int j = 0; j < 2; ++j)
          bf[j] = *(const bf16x8*)&Bs[wn * 32 + j * 16 + l16][kk];
        #pragma unroll
        for (int i = 0; i < 4; ++i)
          #pragma unroll
          for (int j = 0; j < 2; ++j)
            c[i][j] = __builtin_amdgcn_mfma_f32_16x16x32_bf16(af[i], bf[j], c[i][j], 0, 0, 0);
      }
      __syncthreads();
    }
  } else {
    // ---------- expert path: A bf16, B = wdn[e] [512 k][1024 n] fp32 gather-transpose ----------
    int b2 = bid - 512;
    int e = b2 >> 8, rem = b2 & 255;
    n0 = (rem & 15) * BN; m0 = (rem >> 4) * BM;
    int base = offs[e];
    M = offs[e + 1] - base;
    if (m0 >= M) return;
    base_row = base;
    const int NT = FF / BK;   // 8
    const float* W = WDN + (size_t)e * FF * DH;
    const ushort_t* A = HX + (size_t)base * FF;
    int tn = t & 63, tk = (t >> 6) * 16;
    outp = EXPO;

    const ushort_t* arow[4];
    #pragma unroll
    for (int p = 0; p < 4; ++p) {
      int m = m0 + sr + 32 * p;
      int mm = m < M ? m : (M - 1);
      arow[p] = A + (size_t)mm * FF + sc;
    }
    const float* wkb = W + (size_t)tk * DH + n0 + tn;

    uint4 ar[4];
    float br[16];
    #pragma unroll
    for (int p = 0; p < 4; ++p) ar[p] = *(const uint4*)(arow[p]);
    #pragma unroll
    for (int j = 0; j < 16; ++j) br[j] = wkb[(size_t)j * DH];

    for (int kt = 0; kt < NT; ++kt) {
      #pragma unroll
      for (int p = 0; p < 4; ++p)
        *(uint4*)&As[sr + 32 * p][sc] = ar[p];
      {
        union { ushort_t u[8]; uint4 v; } b0, b1;
        #pragma unroll
        for (int j = 0; j < 8; ++j) { b0.u[j] = f2bf(br[j]); b1.u[j] = f2bf(br[8 + j]); }
        *(uint4*)&Bs[tn][tk]     = b0.v;
        *(uint4*)&Bs[tn][tk + 8] = b1.v;
      }
      __syncthreads();
      if (kt + 1 < NT) {
        int ko = (kt + 1) * BK;
        #pragma unroll
        for (int p = 0; p < 4; ++p) ar[p] = *(const uint4*)(arow[p] + ko);
        const float* wk = wkb + (size_t)ko * DH;
        #pragma unroll
        for (int j = 0; j < 16; ++j) br[j] = wk[(size_t)j * DH];
      }
      #pragma unroll
      for (int ks = 0; ks < 2; ++ks) {
        int kk = ks * 32 + qd * 8;
        bf16x8 af[4], bf[2];
        #pragma unroll
        for (int i = 0; i < 4; ++i)
          af[i] = *(const bf16x8*)&As[wm * 64 + i * 16 + l16][kk];
        #pragma unroll
        for (int j = 0; j < 2; ++j)
          bf[j] = *(const bf16x8*)&Bs[wn * 32 + j * 16 + l16][kk];
        #pragma unroll
        for (int i = 0; i < 4; ++i)
          #pragma unroll
          for (int j = 0; j < 2; ++j)
            c[i][j] = __builtin_amdgcn_mfma_f32_16x16x32_bf16(af[i], bf[j], c[i][j], 0, 0, 0);
      }
      __syncthreads();
    }
  }

  // ---------- epilogue: LDS bounce -> coalesced uint4 stores (bf16 out) ----------
  #pragma unroll
  for (int i = 0; i < 4; ++i)
    #pragma unroll
    for (int r = 0; r < 4; ++r) {
      int row = wm * 64 + i * 16 + qd * 4 + r;
      #pragma unroll
      for (int j = 0; j < 2; ++j)
        As[row][wn * 32 + j * 16 + l16] = f2bf(c[i][j][r]);
    }
  __syncthreads();
  #pragma unroll
  for (int p = 0; p < 4; ++p) {
    int m = m0 + sr + 32 * p;
    if (m < M)
      *(uint4*)(outp + (size_t)(base_row + m) * DH + n0 + sc) = *(uint4*)&As[sr + 32 * p][sc];
  }
}

// ---------------- combine: out = sg*(sd0+sd1) + w0*expo[s0] + w1*expo[s1] ----------------
__global__ void combine_kernel(const ushort_t* __restrict__ SD0, const ushort_t* __restrict__ SD1,
                               const ushort_t* __restrict__ EXPO,
                               const float* __restrict__ sgate, const float* __restrict__ wtk,
                               const int* __restrict__ slot_of, float* __restrict__ out) {
  int n = blockIdx.x, t = threadIdx.x;
  float sg = sgate[n];
  float w0 = wtk[n * 2 + 0], w1 = wtk[n * 2 + 1];
  int s0 = slot_of[n * 2 + 0], s1 = slot_of[n * 2 + 1];
  int col = t * 4;
  ushort4 d0 = *(const ushort4*)(SD0 + (size_t)n * DH + col);
  ushort4 d1 = *(const ushort4*)(SD1 + (size_t)n * DH + col);
  ushort4 a  = *(const ushort4*)(EXPO + (size_t)s0 * DH + col);
  ushort4 b  = *(const ushort4*)(EXPO + (size_t)s1 * DH + col);
  float4 o;
  o.x = sg * (bf2f(d0.x) + bf2f(d1.x)) + w0 * bf2f(a.x) + w1 * bf2f(b.x);
  o.y = sg * (bf2f(d0.y) + bf2f(d1.y)) + w0 * bf2f(a.y) + w1 * bf2f(b.y);
  o.z = sg * (bf2f(d0.z) + bf2f(d1.z)) + w0 * bf2f(a.z) + w1 * bf2f(b.z);
  o.w = sg * (bf2f(d0.w) + bf2f(d1.w)) + w0 * bf2f(a.w) + w1 * bf2f(b.w);
  *(float4*)(out + (size_t)n * DH + col) = o;
}

// ---------------- launcher ----------------
extern "C" void kernel_launch(void* const* d_in, const int* in_sizes, int n_in,
                              void* d_out, int out_size, void* d_ws, size_t ws_size,
                              hipStream_t stream) {
  const float* x    = (const float*)d_in[0];   // [2048,1024]
  const float* gw   = (const float*)d_in[1];   // [16,1024]
  const float* wgu  = (const float*)d_in[2];   // [16,1024,1024] (k-major)
  const float* wdn  = (const float*)d_in[3];   // [16,512,1024]  (k-major)
  const float* swg  = (const float*)d_in[4];   // [2816,1024] NT
  const float* swu  = (const float*)d_in[5];   // [2816,1024] NT
  const float* swd  = (const float*)d_in[6];   // [1024,2816] NT
  const float* sgw  = (const float*)d_in[7];   // [1,1024]
  float* out = (float*)d_out;

  char* ws = (char*)d_ws;
  constexpr size_t OFF_HS   = 0;                                        // 11,534,336
  constexpr size_t OFF_HX   = OFF_HS   + (size_t)N_TOK * SFF * 2;       // +4,194,304
  constexpr size_t OFF_SD0  = OFF_HX   + (size_t)4096 * FF * 2;         // +4,194,304
  constexpr size_t OFF_SD1  = OFF_SD0  + (size_t)N_TOK * DH * 2;        // +4,194,304
  constexpr size_t OFF_EXPO = OFF_SD1  + (size_t)N_TOK * DH * 2;        // +8,388,608
  constexpr size_t OFF_TOK  = OFF_EXPO + (size_t)4096 * DH * 2;
  constexpr size_t OFF_OFFS = OFF_TOK  + 4096 * 4;
  constexpr size_t OFF_SEL  = OFF_OFFS + 32 * 4;
  constexpr size_t OFF_WTK  = OFF_SEL  + 4096 * 4;
  constexpr size_t OFF_SG   = OFF_WTK  + 4096 * 4;
  constexpr size_t OFF_SLOT = OFF_SG   + 2048 * 4;                      // end ~32.6 MB

  ushort_t* hs    = (ushort_t*)(ws + OFF_HS);
  ushort_t* hx    = (ushort_t*)(ws + OFF_HX);
  ushort_t* sd0   = (ushort_t*)(ws + OFF_SD0);
  ushort_t* sd1   = (ushort_t*)(ws + OFF_SD1);
  ushort_t* expo  = (ushort_t*)(ws + OFF_EXPO);
  int*      toks  = (int*)(ws + OFF_TOK);
  int*      offs  = (int*)(ws + OFF_OFFS);
  int*      sel   = (int*)(ws + OFF_SEL);
  float*    wtk   = (float*)(ws + OFF_WTK);
  float*    sgate = (float*)(ws + OFF_SG);
  int*      slot_of = (int*)(ws + OFF_SLOT);

  router_kernel<<<N_TOK / 4, 256, 0, stream>>>(x, gw, sgw, sel, wtk, sgate);
  scatter_kernel<<<1, 256, 0, stream>>>(sel, toks, slot_of, offs);
  // gateup: shared 16m*44n = 704, expert 16e*16m*8n = 2048
  gateup_kernel<<<704 + 2048, 256, 0, stream>>>(x, wgu, swg, swu, hx, hs, toks, offs);
  // down: shared 2kz*16m*16n = 512, expert 16e*16m*16n = 4096
  down_kernel<<<512 + 4096, 256, 0, stream>>>(hx, hs, wdn, swd, sd0, sd1, expo, offs);
  combine_kernel<<<N_TOK, 256, 0, stream>>>(sd0, sd1, expo, sgate, wtk, slot_of, out);
}